// Round 13
// baseline (458.609 us; speedup 1.0000x reference)
//
#include <hip/hip_runtime.h>
#include <hip/hip_bf16.h>
#include <hip/hip_cooperative_groups.h>

namespace cg = cooperative_groups;

#define NN 10000
#define EE 320000
#define DD 128
#define TEE 128  // edges per block (edge kernel)
#define COOPB 1024

typedef __attribute__((ext_vector_type(8))) __bf16 bf16x8;
typedef __attribute__((ext_vector_type(2))) __bf16 bf16x2;
typedef __attribute__((ext_vector_type(8))) unsigned short ushort8;
typedef __attribute__((ext_vector_type(4))) float  f32x4;

// fast silu/sigmoid: v_rcp_f32 (~1 ulp) instead of IEEE div sequence.
__device__ __forceinline__ float silu_f(float x) {
    return x * __builtin_amdgcn_rcpf(1.0f + __expf(-x));
}
__device__ __forceinline__ float sigmoid_f(float x) {
    return __builtin_amdgcn_rcpf(1.0f + __expf(-x));
}
__device__ __forceinline__ unsigned pkbf(float a, float b) {
    bf16x2 v; v.x = (__bf16)a; v.y = (__bf16)b;
    return __builtin_bit_cast(unsigned, v);
}
__device__ __forceinline__ unsigned short sbf(float a) {
    return __builtin_bit_cast(unsigned short, (__bf16)a);
}
__device__ __forceinline__ float bf2f(unsigned short u) {
    return __builtin_bit_cast(float, (unsigned)u << 16);
}
__device__ __forceinline__ float atomic_add_f(float* p, float v) {
    return unsafeAtomicAdd(p, v);
}

// ---------------------------------------------------------------------------
// cooperative front kernel: ONE launch for {zero, prep, hist, alloc, scatter, pq}
// 1024 blocks x 256 thr (4 blocks/CU co-resident).
// ---------------------------------------------------------------------------
__global__ __launch_bounds__(256, 4)
void coop_kernel(const int* __restrict__ ei,
                 int* __restrict__ cnt, int* __restrict__ tmp,
                 int* __restrict__ offs, int* __restrict__ ctr,
                 int2* __restrict__ eidx,
                 const float* __restrict__ h, const float* __restrict__ be1,
                 const float* __restrict__ We1, const float* __restrict__ We2,
                 const float* __restrict__ Wc1, const float* __restrict__ Wn1,
                 const float* __restrict__ Wn2,
                 unsigned short* __restrict__ pW,
                 unsigned short* __restrict__ P, unsigned short* __restrict__ Q,
                 float* __restrict__ aggz)
{
    cg::grid_group grid = cg::this_grid();
    const int b    = blockIdx.x;
    const int tid  = threadIdx.x;
    const int gtid = b * 256 + tid;
    const int GT   = COOPB * 256;            // 262144 threads

    // ---- P0: weight pack / zero ints / zero agg ----
    if (gtid < 114688) {
        const int idx = gtid;
        const float* src; int loc, nks, koff = 0;
        if (idx < 16384)       { src = We1; loc = idx;         nks = 4; }
        else if (idx < 32768)  { src = We1; loc = idx - 16384; nks = 4; koff = 128; }
        else if (idx < 49152)  { src = We2; loc = idx - 32768; nks = 4; }
        else if (idx < 65536)  { src = Wc1; loc = idx - 49152; nks = 4; }
        else if (idx < 98304)  { src = Wn1; loc = idx - 65536; nks = 8; }
        else                   { src = Wn2; loc = idx - 98304; nks = 4; }
        const int per_ct = nks * 512;
        const int ct = loc / per_ct;
        const int r  = loc % per_ct;
        const int ks = r >> 9;
        const int r2 = r & 511;
        const int ln = r2 >> 3;
        const int j  = r2 & 7;
        const int k  = ks * 32 + (ln >> 4) * 8 + j + koff;
        const int n  = ct * 16 + (ln & 15);
        pW[idx] = sbf(src[k * DD + n]);
    } else if (gtid < 114688 + 2 * NN) {
        cnt[gtid - 114688] = 0;              // zeroes cnt then tmp (contiguous)
    } else if (gtid == 114688 + 2 * NN) {
        *ctr = 0;
    }
    {
        // zero agg_h + agg_c: 327500 float4
        float4* p = (float4*)aggz;
        for (int i = gtid; i < 327500; i += GT)
            p[i] = make_float4(0.f, 0.f, 0.f, 0.f);
    }
    grid.sync();

    // ---- P1: histogram ----
    for (int e = gtid; e < EE; e += GT)
        atomicAdd(&cnt[ei[e]], 1);
    grid.sync();

    // ---- P2: order-free group allocation ----
    if (gtid < NN) offs[gtid] = atomicAdd(ctr, cnt[gtid]);
    grid.sync();

    // ---- P3: scatter grouped (row,col) records ----
    for (int e = gtid; e < EE; e += GT) {
        const int r = ei[e];
        const int c = ei[EE + e];
        const int pos = offs[r] + atomicAdd(&tmp[r], 1);
        eidx[pos] = make_int2(r, c);
    }

    // ---- P4: pq (blocks 0..312, 32 nodes each) — no sync needed vs P3 ----
    if (b >= 313) return;
    __shared__ __align__(16) unsigned short sAbuf[32 * 128];  // 8KB
    const int w    = tid >> 6;
    const int lane = tid & 63;
    const int g    = lane >> 4;
    const int l15  = lane & 15;
    const int n0   = b * 32;
    char* const sAb = (char*)sAbuf;

#pragma unroll
    for (int i = 0; i < 2; ++i) {
        const int idx = tid * 2 + i;          // 0..511
        const int row = idx >> 4, c = idx & 15;
        const int n = n0 + row;
        float4 a = make_float4(0.f, 0.f, 0.f, 0.f);
        float4 bb = make_float4(0.f, 0.f, 0.f, 0.f);
        if (n < NN) {
            a  = *(const float4*)&h[(size_t)n * DD + c * 8];
            bb = *(const float4*)&h[(size_t)n * DD + c * 8 + 4];
        }
        uint4 pk;
        pk.x = pkbf(a.x, a.y);  pk.y = pkbf(a.z, a.w);
        pk.z = pkbf(bb.x, bb.y); pk.w = pkbf(bb.z, bb.w);
        *(uint4*)(sAb + row * 256 + ((c * 16) ^ ((row & 7) << 4))) = pk;
    }
    __syncthreads();

    f32x4 accP[2][2], accQ[2][2];
    {
        float be1c[2];
#pragma unroll
        for (int ctl = 0; ctl < 2; ++ctl)
            be1c[ctl] = be1[w * 32 + ctl * 16 + l15];
#pragma unroll
        for (int rt = 0; rt < 2; ++rt)
#pragma unroll
            for (int ctl = 0; ctl < 2; ++ctl)
#pragma unroll
                for (int j = 0; j < 4; ++j) {
                    accP[rt][ctl][j] = be1c[ctl];
                    accQ[rt][ctl][j] = 0.f;
                }
    }
    const unsigned short* pWa = pW;
    const unsigned short* pWb = pW + 16384;
#pragma unroll 1
    for (int ks = 0; ks < 4; ++ks) {
        bf16x8 a[2];
#pragma unroll
        for (int rt = 0; rt < 2; ++rt) {
            const int row = rt * 16 + l15;
            const int byc = g * 16 + ks * 64;
            a[rt] = *(const bf16x8*)(sAb + row * 256 + (byc ^ ((row & 7) << 4)));
        }
        const bf16x8 pa0 = *(const bf16x8*)&pWa[(((2 * w + 0) * 4 + ks) * 64 + lane) * 8];
        const bf16x8 pa1 = *(const bf16x8*)&pWa[(((2 * w + 1) * 4 + ks) * 64 + lane) * 8];
        const bf16x8 pb0 = *(const bf16x8*)&pWb[(((2 * w + 0) * 4 + ks) * 64 + lane) * 8];
        const bf16x8 pb1 = *(const bf16x8*)&pWb[(((2 * w + 1) * 4 + ks) * 64 + lane) * 8];
#pragma unroll
        for (int rt = 0; rt < 2; ++rt) {
            accP[rt][0] = __builtin_amdgcn_mfma_f32_16x16x32_bf16(a[rt], pa0, accP[rt][0], 0, 0, 0);
            accP[rt][1] = __builtin_amdgcn_mfma_f32_16x16x32_bf16(a[rt], pa1, accP[rt][1], 0, 0, 0);
            accQ[rt][0] = __builtin_amdgcn_mfma_f32_16x16x32_bf16(a[rt], pb0, accQ[rt][0], 0, 0, 0);
            accQ[rt][1] = __builtin_amdgcn_mfma_f32_16x16x32_bf16(a[rt], pb1, accQ[rt][1], 0, 0, 0);
        }
    }
#pragma unroll
    for (int rt = 0; rt < 2; ++rt)
#pragma unroll
        for (int ctl = 0; ctl < 2; ++ctl)
#pragma unroll
            for (int j = 0; j < 4; ++j) {
                const int row = rt * 16 + g * 4 + j;
                const int n = n0 + row;
                if (n < NN) {
                    const int col = w * 32 + ctl * 16 + l15;
                    P[(size_t)n * DD + col] = sbf(accP[rt][ctl][j]);
                    Q[(size_t)n * DD + col] = sbf(accQ[rt][ctl][j]);
                }
            }
}

// ---------------------------------------------------------------------------
// edge kernel: 128 grouped edges/block, 8 waves (512 thr), MFMA 16x16x32.
// (unchanged from round 12)
// ---------------------------------------------------------------------------
__global__ __launch_bounds__(512, 6)
void edge_kernel(const int2* __restrict__ eidx,
                 const float* __restrict__ coord,
                 const unsigned short* __restrict__ P, const unsigned short* __restrict__ Q,
                 const float* __restrict__ We1,
                 const float* __restrict__ be2,
                 const float* __restrict__ Wa, const float* __restrict__ ba,
                 const float* __restrict__ bc1, const float* __restrict__ Wc2,
                 const unsigned short* __restrict__ pW,
                 float* __restrict__ agg_h, float* __restrict__ agg_c)
{
    __shared__ __align__(16) unsigned short sM[128 * 128];   // 32KB
    __shared__ __align__(16) float sWred[4][128];
    __shared__ __align__(16) int   sRow[128];
    __shared__ int   sCol[128];
    __shared__ __align__(16) float sRad[128];
    __shared__ __align__(16) float sAtt[128];
    __shared__ float sCd[128][3];

    const int tid  = threadIdx.x;
    const int w    = tid >> 6;
    const int lane = tid & 63;
    const int g    = lane >> 4;
    const int l15  = lane & 15;
    const int rh   = w >> 2;
    const int cq   = w & 3;
    const int rb   = rh * 64;
    const int e0g  = blockIdx.x * TEE;
    char* const sMb = (char*)sM;

    // ---- phase 0: indices (single int2 read), coord diff, radial ----
    if (tid < TEE) {
        const int2 rc = eidx[e0g + tid];
        sRow[tid] = rc.x; sCol[tid] = rc.y;
        const float dx = coord[rc.x * 3 + 0] - coord[rc.y * 3 + 0];
        const float dy = coord[rc.x * 3 + 1] - coord[rc.y * 3 + 1];
        const float dz = coord[rc.x * 3 + 2] - coord[rc.y * 3 + 2];
        sCd[tid][0] = dx; sCd[tid][1] = dy; sCd[tid][2] = dz;
        sRad[tid] = dx * dx + dy * dy + dz * dz;
    }
    __syncthreads();   // B0

    // ---- phase 1: m1 = silu(P[row] + Q[col] + rad*wr) -> sM (bf16 swizzled) ----
    {
        const int el  = tid >> 2;
        const int sub = tid & 3;
        const int rg = sRow[el], cg = sCol[el];
        const float rad = sRad[el];
        const unsigned short* Prow = P + (size_t)rg * DD;
        const unsigned short* Qrow = Q + (size_t)cg * DD;
        const float* We1r = We1 + 256 * DD;
#pragma unroll
        for (int i = 0; i < 4; ++i) {
            const int c8 = sub * 4 + i;
            const ushort8 pu = __builtin_bit_cast(ushort8, *(const bf16x8*)&Prow[c8 * 8]);
            const ushort8 qu = __builtin_bit_cast(ushort8, *(const bf16x8*)&Qrow[c8 * 8]);
            const float4 w0 = *(const float4*)&We1r[c8 * 8];
            const float4 w1 = *(const float4*)&We1r[c8 * 8 + 4];
            float x[8];
            x[0] = fmaf(rad, w0.x, bf2f(pu[0]) + bf2f(qu[0]));
            x[1] = fmaf(rad, w0.y, bf2f(pu[1]) + bf2f(qu[1]));
            x[2] = fmaf(rad, w0.z, bf2f(pu[2]) + bf2f(qu[2]));
            x[3] = fmaf(rad, w0.w, bf2f(pu[3]) + bf2f(qu[3]));
            x[4] = fmaf(rad, w1.x, bf2f(pu[4]) + bf2f(qu[4]));
            x[5] = fmaf(rad, w1.y, bf2f(pu[5]) + bf2f(qu[5]));
            x[6] = fmaf(rad, w1.z, bf2f(pu[6]) + bf2f(qu[6]));
            x[7] = fmaf(rad, w1.w, bf2f(pu[7]) + bf2f(qu[7]));
            uint4 pk;
            pk.x = pkbf(silu_f(x[0]), silu_f(x[1]));
            pk.y = pkbf(silu_f(x[2]), silu_f(x[3]));
            pk.z = pkbf(silu_f(x[4]), silu_f(x[5]));
            pk.w = pkbf(silu_f(x[6]), silu_f(x[7]));
            *(uint4*)(sMb + el * 256 + ((c8 * 16) ^ ((el & 7) << 4))) = pk;
        }
    }
    __syncthreads();   // B1

    f32x4 acc[4][2];

    // ---- GEMM2: m = silu(m1 @ We2 + be2) (m stays in registers) ----
    {
        float be2c[2];
#pragma unroll
        for (int ctl = 0; ctl < 2; ++ctl)
            be2c[ctl] = be2[cq * 32 + ctl * 16 + l15];
#pragma unroll
        for (int rt = 0; rt < 4; ++rt)
#pragma unroll
            for (int ctl = 0; ctl < 2; ++ctl)
#pragma unroll
                for (int j = 0; j < 4; ++j)
                    acc[rt][ctl][j] = be2c[ctl];
        const unsigned short* pWe2 = pW + 32768;
#pragma unroll 1
        for (int ks = 0; ks < 4; ++ks) {
            bf16x8 a[4];
#pragma unroll
            for (int rt = 0; rt < 4; ++rt) {
                const int row = rb + rt * 16 + l15;
                const int byc = g * 16 + ks * 64;
                a[rt] = *(const bf16x8*)(sMb + row * 256 + (byc ^ ((row & 7) << 4)));
            }
            const bf16x8 b0 = *(const bf16x8*)&pWe2[(((2 * cq + 0) * 4 + ks) * 64 + lane) * 8];
            const bf16x8 b1 = *(const bf16x8*)&pWe2[(((2 * cq + 1) * 4 + ks) * 64 + lane) * 8];
#pragma unroll
            for (int rt = 0; rt < 4; ++rt) {
                acc[rt][0] = __builtin_amdgcn_mfma_f32_16x16x32_bf16(a[rt], b0, acc[rt][0], 0, 0, 0);
                acc[rt][1] = __builtin_amdgcn_mfma_f32_16x16x32_bf16(a[rt], b1, acc[rt][1], 0, 0, 0);
            }
        }
    }
#pragma unroll
    for (int rt = 0; rt < 4; ++rt)
#pragma unroll
        for (int ctl = 0; ctl < 2; ++ctl)
#pragma unroll
            for (int j = 0; j < 4; ++j)
                acc[rt][ctl][j] = silu_f(acc[rt][ctl][j]);

    // ---- attention partials: sum_col m*Wa -> sWred[cq] ----
    {
        float wac[2];
#pragma unroll
        for (int ctl = 0; ctl < 2; ++ctl)
            wac[ctl] = Wa[cq * 32 + ctl * 16 + l15];
        float part[4][4];
#pragma unroll
        for (int rt = 0; rt < 4; ++rt)
#pragma unroll
            for (int j = 0; j < 4; ++j)
                part[rt][j] = fmaf(acc[rt][0][j], wac[0], acc[rt][1][j] * wac[1]);
#pragma unroll
        for (int msk = 1; msk < 16; msk <<= 1)
#pragma unroll
            for (int rt = 0; rt < 4; ++rt)
#pragma unroll
                for (int j = 0; j < 4; ++j)
                    part[rt][j] += __shfl_xor(part[rt][j], msk);
        if (l15 == 0) {
#pragma unroll
            for (int rt = 0; rt < 4; ++rt) {
                float4 p4 = make_float4(part[rt][0], part[rt][1], part[rt][2], part[rt][3]);
                *(float4*)&sWred[cq][rb + rt * 16 + g * 4] = p4;
            }
        }
    }
    __syncthreads();   // B2

    // ---- write m -> sM (bf16); att finalize in parallel ----
#pragma unroll
    for (int rt = 0; rt < 4; ++rt)
#pragma unroll
        for (int ctl = 0; ctl < 2; ++ctl)
#pragma unroll
            for (int j = 0; j < 4; ++j) {
                const int row = rb + rt * 16 + g * 4 + j;
                const int col = cq * 32 + ctl * 16 + l15;
                *(unsigned short*)(sMb + row * 256 + ((col * 2) ^ ((row & 7) << 4)))
                    = sbf(acc[rt][ctl][j]);
            }
    if (tid < TEE) {
        const float s = sWred[0][tid] + sWred[1][tid] + sWred[2][tid] + sWred[3][tid];
        sAtt[tid] = sigmoid_f(s + ba[0]);
    }
    __syncthreads();   // B3

    // ---- GEMMc: Y = m @ Wc1; w = sum_c silu(att*Y + bc1)*Wc2 ----
    {
        float bc1c[2];
#pragma unroll
        for (int ctl = 0; ctl < 2; ++ctl)
            bc1c[ctl] = bc1[cq * 32 + ctl * 16 + l15];
#pragma unroll
        for (int rt = 0; rt < 4; ++rt)
#pragma unroll
            for (int ctl = 0; ctl < 2; ++ctl)
#pragma unroll
                for (int j = 0; j < 4; ++j)
                    acc[rt][ctl][j] = 0.f;
        const unsigned short* pWc1 = pW + 49152;
#pragma unroll 1
        for (int ks = 0; ks < 4; ++ks) {
            bf16x8 a[4];
#pragma unroll
            for (int rt = 0; rt < 4; ++rt) {
                const int row = rb + rt * 16 + l15;
                const int byc = g * 16 + ks * 64;
                a[rt] = *(const bf16x8*)(sMb + row * 256 + (byc ^ ((row & 7) << 4)));
            }
            const bf16x8 b0 = *(const bf16x8*)&pWc1[(((2 * cq + 0) * 4 + ks) * 64 + lane) * 8];
            const bf16x8 b1 = *(const bf16x8*)&pWc1[(((2 * cq + 1) * 4 + ks) * 64 + lane) * 8];
#pragma unroll
            for (int rt = 0; rt < 4; ++rt) {
                acc[rt][0] = __builtin_amdgcn_mfma_f32_16x16x32_bf16(a[rt], b0, acc[rt][0], 0, 0, 0);
                acc[rt][1] = __builtin_amdgcn_mfma_f32_16x16x32_bf16(a[rt], b1, acc[rt][1], 0, 0, 0);
            }
        }
        float wcc[2];
#pragma unroll
        for (int ctl = 0; ctl < 2; ++ctl)
            wcc[ctl] = Wc2[cq * 32 + ctl * 16 + l15];
        float part[4][4];
#pragma unroll
        for (int rt = 0; rt < 4; ++rt) {
            const float4 a4 = *(const float4*)&sAtt[rb + rt * 16 + g * 4];
            const float at[4] = {a4.x, a4.y, a4.z, a4.w};
#pragma unroll
            for (int j = 0; j < 4; ++j) {
                const float z0 = silu_f(fmaf(at[j], acc[rt][0][j], bc1c[0]));
                const float z1 = silu_f(fmaf(at[j], acc[rt][1][j], bc1c[1]));
                part[rt][j] = fmaf(z0, wcc[0], z1 * wcc[1]);
            }
        }
#pragma unroll
        for (int msk = 1; msk < 16; msk <<= 1)
#pragma unroll
            for (int rt = 0; rt < 4; ++rt)
#pragma unroll
                for (int j = 0; j < 4; ++j)
                    part[rt][j] += __shfl_xor(part[rt][j], msk);
        if (l15 == 0) {
#pragma unroll
            for (int rt = 0; rt < 4; ++rt) {
                float4 p4 = make_float4(part[rt][0], part[rt][1], part[rt][2], part[rt][3]);
                *(float4*)&sWred[cq][rb + rt * 16 + g * 4] = p4;
            }
        }
    }
    __syncthreads();   // B4

    // ---- agg_h segmented reduce: ef[e,col] = sAtt[e]*m[e,col] on the fly ----
    {
        const int col = tid & 127;
        const int seg = tid >> 7;           // 4 segments of 32 edges
        const int ebeg = seg * 32;
        float a = 0.f;
        int cur = sRow[ebeg];
#pragma unroll 1
        for (int e = ebeg; e < ebeg + 32; ++e) {
            const int r = sRow[e];
            if (r != cur) {
                atomic_add_f(&agg_h[(size_t)cur * DD + col], a);
                a = 0.f; cur = r;
            }
            const unsigned short u =
                *(const unsigned short*)(sMb + e * 256 + ((col * 2) ^ ((e & 7) << 4)));
            a = fmaf(sAtt[e], bf2f(u), a);
        }
        atomic_add_f(&agg_h[(size_t)cur * DD + col], a);
    }

    // ---- agg_c segmented reduce (4 segs x 32 edges) ----
    if (tid < 12) {
        const int c = tid % 3;
        const int seg = tid / 3;
        const int ebeg = seg * 32;
        float a = 0.f;
        int cur = sRow[ebeg];
#pragma unroll 1
        for (int e = ebeg; e < ebeg + 32; ++e) {
            const int r = sRow[e];
            if (r != cur) {
                atomic_add_f(&agg_c[cur * 3 + c], a);
                a = 0.f; cur = r;
            }
            const float wv = sWred[0][e] + sWred[1][e] + sWred[2][e] + sWred[3][e];
            a += sCd[e][c] * wv;
        }
        atomic_add_f(&agg_c[cur * 3 + c], a);
    }
}

// ---------------------------------------------------------------------------
// node kernel: 32 nodes/block (313 blocks), 4 waves, MFMA. (unchanged)
// ---------------------------------------------------------------------------
__global__ __launch_bounds__(256, 2)
void node_kernel(const float* __restrict__ h, const float* __restrict__ coord,
                 const float* __restrict__ bn1, const float* __restrict__ bn2,
                 const unsigned short* __restrict__ pW,
                 const float* __restrict__ agg_h, const float* __restrict__ agg_c,
                 const int* __restrict__ cnt,
                 float* __restrict__ hout, float* __restrict__ cout)
{
    __shared__ __align__(16) unsigned short sAbuf[32 * 256];   // 16KB

    const int tid  = threadIdx.x;
    const int w    = tid >> 6;
    const int lane = tid & 63;
    const int g    = lane >> 4;
    const int l15  = lane & 15;
    const int n0   = blockIdx.x * 32;
    char* const sAb = (char*)sAbuf;

    {
        const int halfsel = (lane >= 32) ? 1 : 0;
        const int bytec   = (lane & 31) * 8 + halfsel * 256;
        const float* src  = halfsel ? agg_h : h;
#pragma unroll 4
        for (int s = 0; s < 8; ++s) {
            const int row = w * 8 + s;
            const int n = n0 + row;
            float4 v = make_float4(0.f, 0.f, 0.f, 0.f);
            if (n < NN) v = *(const float4*)&src[(size_t)n * DD + (lane & 31) * 4];
            uint2 pk;
            pk.x = pkbf(v.x, v.y);
            pk.y = pkbf(v.z, v.w);
            *(uint2*)(sAb + row * 512 + (bytec ^ ((row & 7) << 4))) = pk;
        }
    }
    __syncthreads();

    f32x4 acc[2][2];

    {
        float bc[2];
#pragma unroll
        for (int ctl = 0; ctl < 2; ++ctl)
            bc[ctl] = bn1[w * 32 + ctl * 16 + l15];
#pragma unroll
        for (int rt = 0; rt < 2; ++rt)
#pragma unroll
            for (int ctl = 0; ctl < 2; ++ctl)
#pragma unroll
                for (int j = 0; j < 4; ++j)
                    acc[rt][ctl][j] = bc[ctl];
        const unsigned short* pWn1 = pW + 65536;
#pragma unroll 1
        for (int ks = 0; ks < 8; ++ks) {
            bf16x8 a[2];
#pragma unroll
            for (int rt = 0; rt < 2; ++rt) {
                const int row = rt * 16 + l15;
                const int byc = g * 16 + ks * 64;
                a[rt] = *(const bf16x8*)(sAb + row * 512 + (byc ^ ((row & 7) << 4)));
            }
            const bf16x8 b0 = *(const bf16x8*)&pWn1[(((2 * w + 0) * 8 + ks) * 64 + lane) * 8];
            const bf16x8 b1 = *(const bf16x8*)&pWn1[(((2 * w + 1) * 8 + ks) * 64 + lane) * 8];
#pragma unroll
            for (int rt = 0; rt < 2; ++rt) {
                acc[rt][0] = __builtin_amdgcn_mfma_f32_16x16x32_bf16(a[rt], b0, acc[rt][0], 0, 0, 0);
                acc[rt][1] = __builtin_amdgcn_mfma_f32_16x16x32_bf16(a[rt], b1, acc[rt][1], 0, 0, 0);
            }
        }
    }
    __syncthreads();
#pragma unroll
    for (int rt = 0; rt < 2; ++rt)
#pragma unroll
        for (int ctl = 0; ctl < 2; ++ctl)
#pragma unroll
            for (int j = 0; j < 4; ++j) {
                const int row = rt * 16 + g * 4 + j;
                const int col = w * 32 + ctl * 16 + l15;
                *(unsigned short*)(sAb + row * 256 + ((col * 2) ^ ((row & 7) << 4)))
                    = sbf(silu_f(acc[rt][ctl][j]));
            }
    __syncthreads();

    {
        float bc[2];
#pragma unroll
        for (int ctl = 0; ctl < 2; ++ctl)
            bc[ctl] = bn2[w * 32 + ctl * 16 + l15];
#pragma unroll
        for (int rt = 0; rt < 2; ++rt)
#pragma unroll
            for (int ctl = 0; ctl < 2; ++ctl)
#pragma unroll
                for (int j = 0; j < 4; ++j)
                    acc[rt][ctl][j] = bc[ctl];
        const unsigned short* pWn2 = pW + 98304;
#pragma unroll 1
        for (int ks = 0; ks < 4; ++ks) {
            bf16x8 a[2];
#pragma unroll
            for (int rt = 0; rt < 2; ++rt) {
                const int row = rt * 16 + l15;
                const int byc = g * 16 + ks * 64;
                a[rt] = *(const bf16x8*)(sAb + row * 256 + (byc ^ ((row & 7) << 4)));
            }
            const bf16x8 b0 = *(const bf16x8*)&pWn2[(((2 * w + 0) * 4 + ks) * 64 + lane) * 8];
            const bf16x8 b1 = *(const bf16x8*)&pWn2[(((2 * w + 1) * 4 + ks) * 64 + lane) * 8];
#pragma unroll
            for (int rt = 0; rt < 2; ++rt) {
                acc[rt][0] = __builtin_amdgcn_mfma_f32_16x16x32_bf16(a[rt], b0, acc[rt][0], 0, 0, 0);
                acc[rt][1] = __builtin_amdgcn_mfma_f32_16x16x32_bf16(a[rt], b1, acc[rt][1], 0, 0, 0);
            }
        }
    }
#pragma unroll
    for (int rt = 0; rt < 2; ++rt)
#pragma unroll
        for (int ctl = 0; ctl < 2; ++ctl)
#pragma unroll
            for (int j = 0; j < 4; ++j) {
                const int row = rt * 16 + g * 4 + j;
                const int n = n0 + row;
                if (n < NN) {
                    const int col = w * 32 + ctl * 16 + l15;
                    hout[(size_t)n * DD + col] = h[(size_t)n * DD + col] + acc[rt][ctl][j];
                }
            }

    if (tid < 96) {
        const int e = tid / 3, c = tid % 3;
        const int n = n0 + e;
        if (n < NN) {
            const float cn = fmaxf((float)cnt[n], 1.0f);
            cout[n * 3 + c] = coord[n * 3 + c] + agg_c[n * 3 + c] / cn;
        }
    }
}

extern "C" void kernel_launch(void* const* d_in, const int* in_sizes, int n_in,
                              void* d_out, int out_size, void* d_ws, size_t ws_size,
                              hipStream_t stream)
{
    const float* h     = (const float*)d_in[0];
    const int*   ei    = (const int*)  d_in[1];
    const float* coord = (const float*)d_in[2];
    const float* We1   = (const float*)d_in[3];
    const float* be1   = (const float*)d_in[4];
    const float* We2   = (const float*)d_in[5];
    const float* be2   = (const float*)d_in[6];
    const float* Wa    = (const float*)d_in[7];
    const float* ba    = (const float*)d_in[8];
    const float* Wn1   = (const float*)d_in[9];
    const float* bn1   = (const float*)d_in[10];
    const float* Wn2   = (const float*)d_in[11];
    const float* bn2   = (const float*)d_in[12];
    const float* Wc1   = (const float*)d_in[13];
    const float* bc1   = (const float*)d_in[14];
    const float* Wc2   = (const float*)d_in[15];

    // ws layout
    float* agg_h   = (float*)d_ws;                   // 1,280,000 f
    float* agg_c   = agg_h + (size_t)NN * DD;        //    30,000 f
    int*   cnt_i   = (int*)(agg_c + (size_t)NN * 3); //    10,000 i
    int*   tmp_i   = cnt_i + NN;                     //    10,000 i
    int*   offs    = tmp_i + NN;                     //    10,016 i (incl. ctr @ +10008)
    int2*  eidx    = (int2*)(offs + 10016);          //   320,000 int2
    unsigned short* pW = (unsigned short*)(eidx + EE);     // 114,688 u16
    unsigned short* P  = pW + 114688;                      // 1,280,000 u16
    unsigned short* Q  = P + (size_t)NN * DD;              // 1,280,000 u16
    int* ctr = offs + 10008;

    {
        void* args[] = {
            (void*)&ei, (void*)&cnt_i, (void*)&tmp_i, (void*)&offs, (void*)&ctr,
            (void*)&eidx, (void*)&h, (void*)&be1, (void*)&We1, (void*)&We2,
            (void*)&Wc1, (void*)&Wn1, (void*)&Wn2, (void*)&pW,
            (void*)&P, (void*)&Q, (void*)&agg_h
        };
        (void)hipLaunchCooperativeKernel((const void*)coop_kernel,
                                         dim3(COOPB), dim3(256), args, 0, stream);
    }

    edge_kernel<<<EE / TEE, 512, 0, stream>>>(eidx, coord, P, Q, We1, be2,
                                              Wa, ba, bc1, Wc2, pW, agg_h, agg_c);

    float* hout = (float*)d_out;
    float* cout = hout + (size_t)NN * DD;
    node_kernel<<<313, 256, 0, stream>>>(h, coord, bn1, bn2, pW,
                                         agg_h, agg_c, cnt_i, hout, cout);
}

// Round 14
// 163.950 us; speedup vs baseline: 2.7973x; 2.7973x over previous
//
#include <hip/hip_runtime.h>
#include <hip/hip_bf16.h>

#define NN 10000
#define EE 320000
#define DD 128
#define TEE 128  // edges per block (edge kernel)

typedef __attribute__((ext_vector_type(8))) __bf16 bf16x8;
typedef __attribute__((ext_vector_type(2))) __bf16 bf16x2;
typedef __attribute__((ext_vector_type(8))) unsigned short ushort8;
typedef __attribute__((ext_vector_type(4))) float  f32x4;

// fast silu/sigmoid: v_rcp_f32 (~1 ulp) instead of IEEE div sequence.
__device__ __forceinline__ float silu_f(float x) {
    return x * __builtin_amdgcn_rcpf(1.0f + __expf(-x));
}
__device__ __forceinline__ float sigmoid_f(float x) {
    return __builtin_amdgcn_rcpf(1.0f + __expf(-x));
}
__device__ __forceinline__ unsigned pkbf(float a, float b) {
    bf16x2 v; v.x = (__bf16)a; v.y = (__bf16)b;
    return __builtin_bit_cast(unsigned, v);
}
__device__ __forceinline__ unsigned short sbf(float a) {
    return __builtin_bit_cast(unsigned short, (__bf16)a);
}
__device__ __forceinline__ float bf2f(unsigned short u) {
    return __builtin_bit_cast(float, (unsigned)u << 16);
}
__device__ __forceinline__ float atomic_add_f(float* p, float v) {
    return unsafeAtomicAdd(p, v);
}

// ---------------------------------------------------------------------------
// K1 fused: blocks [0,313) hist, [313,761) prep, [761,1081) zero agg
// ---------------------------------------------------------------------------
__global__ __launch_bounds__(256)
void front_kernel(const int* __restrict__ ei, int* __restrict__ cnt,
                  const float* __restrict__ We1, const float* __restrict__ We2,
                  const float* __restrict__ Wc1, const float* __restrict__ Wn1,
                  const float* __restrict__ Wn2, unsigned short* __restrict__ pW,
                  float* __restrict__ aggz)
{
    const int b = blockIdx.x;
    const int tid = threadIdx.x;
    if (b < 313) {
        const int t4 = b * 256 + tid;
        if (t4 < EE / 4) {
            const int4 e4 = *(const int4*)&ei[t4 * 4];
            atomicAdd(&cnt[e4.x], 1);
            atomicAdd(&cnt[e4.y], 1);
            atomicAdd(&cnt[e4.z], 1);
            atomicAdd(&cnt[e4.w], 1);
        }
    } else if (b < 761) {
        const int idx = (b - 313) * 256 + tid;
        const float* src; int loc, nks, koff = 0;
        if (idx < 16384)       { src = We1; loc = idx;         nks = 4; }
        else if (idx < 32768)  { src = We1; loc = idx - 16384; nks = 4; koff = 128; }
        else if (idx < 49152)  { src = We2; loc = idx - 32768; nks = 4; }
        else if (idx < 65536)  { src = Wc1; loc = idx - 49152; nks = 4; }
        else if (idx < 98304)  { src = Wn1; loc = idx - 65536; nks = 8; }
        else                   { src = Wn2; loc = idx - 98304; nks = 4; }
        const int per_ct = nks * 512;
        const int ct = loc / per_ct;
        const int r  = loc % per_ct;
        const int ks = r >> 9;
        const int r2 = r & 511;
        const int ln = r2 >> 3;
        const int j  = r2 & 7;
        const int k  = ks * 32 + (ln >> 4) * 8 + j + koff;
        const int n  = ct * 16 + (ln & 15);
        pW[idx] = sbf(src[k * DD + n]);
    } else {
        const int base = ((b - 761) * 256 + tid) * 4;
        float4* p = (float4*)aggz;
#pragma unroll
        for (int k = 0; k < 4; ++k) {
            const int i = base + k;
            if (i < 327500) p[i] = make_float4(0.f, 0.f, 0.f, 0.f);
        }
    }
}

// ---------------------------------------------------------------------------
// alloc: order-free group allocation (grouping, not sorting, is sufficient)
// ---------------------------------------------------------------------------
__global__ __launch_bounds__(256)
void alloc_kernel(const int* __restrict__ cnt, int* __restrict__ offs,
                  int* __restrict__ ctr)
{
    const int n = blockIdx.x * 256 + threadIdx.x;
    if (n < NN) offs[n] = atomicAdd(ctr, cnt[n]);
}

// ---------------------------------------------------------------------------
// K2 fused: blocks [0,1250) scatter (post-increments offs directly),
//           [1250,1563) pq (32 nodes/block)
// ---------------------------------------------------------------------------
__global__ __launch_bounds__(256, 2)
void mid_kernel(const int* __restrict__ ei, int* __restrict__ offs,
                int2* __restrict__ eidx,
                const float* __restrict__ h, const float* __restrict__ be1,
                const unsigned short* __restrict__ pW,
                unsigned short* __restrict__ P, unsigned short* __restrict__ Q)
{
    const int b = blockIdx.x;
    const int tid = threadIdx.x;
    if (b < 1250) {
        const int e = b * 256 + tid;
        if (e < EE) {
            const int r = ei[e];
            const int c = ei[EE + e];
            const int pos = atomicAdd(&offs[r], 1);   // offs consumed in place
            eidx[pos] = make_int2(r, c);
        }
        return;
    }
    // ---- pq part: 32 nodes/block ----
    __shared__ __align__(16) unsigned short sAbuf[32 * 128];  // 8KB
    const int w    = tid >> 6;
    const int lane = tid & 63;
    const int g    = lane >> 4;
    const int l15  = lane & 15;
    const int n0   = (b - 1250) * 32;
    char* const sAb = (char*)sAbuf;

#pragma unroll
    for (int i = 0; i < 2; ++i) {
        const int idx = tid * 2 + i;          // 0..511
        const int row = idx >> 4, c = idx & 15;
        const int n = n0 + row;
        float4 a = make_float4(0.f, 0.f, 0.f, 0.f);
        float4 bb = make_float4(0.f, 0.f, 0.f, 0.f);
        if (n < NN) {
            a  = *(const float4*)&h[(size_t)n * DD + c * 8];
            bb = *(const float4*)&h[(size_t)n * DD + c * 8 + 4];
        }
        uint4 pk;
        pk.x = pkbf(a.x, a.y);  pk.y = pkbf(a.z, a.w);
        pk.z = pkbf(bb.x, bb.y); pk.w = pkbf(bb.z, bb.w);
        *(uint4*)(sAb + row * 256 + ((c * 16) ^ ((row & 7) << 4))) = pk;
    }
    __syncthreads();

    f32x4 accP[2][2], accQ[2][2];
    {
        float be1c[2];
#pragma unroll
        for (int ctl = 0; ctl < 2; ++ctl)
            be1c[ctl] = be1[w * 32 + ctl * 16 + l15];
#pragma unroll
        for (int rt = 0; rt < 2; ++rt)
#pragma unroll
            for (int ctl = 0; ctl < 2; ++ctl)
#pragma unroll
                for (int j = 0; j < 4; ++j) {
                    accP[rt][ctl][j] = be1c[ctl];
                    accQ[rt][ctl][j] = 0.f;
                }
    }
    const unsigned short* pWa = pW;
    const unsigned short* pWb = pW + 16384;
#pragma unroll 1
    for (int ks = 0; ks < 4; ++ks) {
        bf16x8 a[2];
#pragma unroll
        for (int rt = 0; rt < 2; ++rt) {
            const int row = rt * 16 + l15;
            const int byc = g * 16 + ks * 64;
            a[rt] = *(const bf16x8*)(sAb + row * 256 + (byc ^ ((row & 7) << 4)));
        }
        const bf16x8 pa0 = *(const bf16x8*)&pWa[(((2 * w + 0) * 4 + ks) * 64 + lane) * 8];
        const bf16x8 pa1 = *(const bf16x8*)&pWa[(((2 * w + 1) * 4 + ks) * 64 + lane) * 8];
        const bf16x8 pb0 = *(const bf16x8*)&pWb[(((2 * w + 0) * 4 + ks) * 64 + lane) * 8];
        const bf16x8 pb1 = *(const bf16x8*)&pWb[(((2 * w + 1) * 4 + ks) * 64 + lane) * 8];
#pragma unroll
        for (int rt = 0; rt < 2; ++rt) {
            accP[rt][0] = __builtin_amdgcn_mfma_f32_16x16x32_bf16(a[rt], pa0, accP[rt][0], 0, 0, 0);
            accP[rt][1] = __builtin_amdgcn_mfma_f32_16x16x32_bf16(a[rt], pa1, accP[rt][1], 0, 0, 0);
            accQ[rt][0] = __builtin_amdgcn_mfma_f32_16x16x32_bf16(a[rt], pb0, accQ[rt][0], 0, 0, 0);
            accQ[rt][1] = __builtin_amdgcn_mfma_f32_16x16x32_bf16(a[rt], pb1, accQ[rt][1], 0, 0, 0);
        }
    }
#pragma unroll
    for (int rt = 0; rt < 2; ++rt)
#pragma unroll
        for (int ctl = 0; ctl < 2; ++ctl)
#pragma unroll
            for (int j = 0; j < 4; ++j) {
                const int row = rt * 16 + g * 4 + j;
                const int n = n0 + row;
                if (n < NN) {
                    const int col = w * 32 + ctl * 16 + l15;
                    P[(size_t)n * DD + col] = sbf(accP[rt][ctl][j]);
                    Q[(size_t)n * DD + col] = sbf(accQ[rt][ctl][j]);
                }
            }
}

// ---------------------------------------------------------------------------
// edge kernel: 128 grouped edges/block, 8 waves (512 thr), MFMA 16x16x32.
// att factored out of GEMMc; m (not ef) lives in LDS. 5 barriers.
// ---------------------------------------------------------------------------
__global__ __launch_bounds__(512, 6)
void edge_kernel(const int2* __restrict__ eidx,
                 const float* __restrict__ coord,
                 const unsigned short* __restrict__ P, const unsigned short* __restrict__ Q,
                 const float* __restrict__ We1,
                 const float* __restrict__ be2,
                 const float* __restrict__ Wa, const float* __restrict__ ba,
                 const float* __restrict__ bc1, const float* __restrict__ Wc2,
                 const unsigned short* __restrict__ pW,
                 float* __restrict__ agg_h, float* __restrict__ agg_c)
{
    __shared__ __align__(16) unsigned short sM[128 * 128];   // 32KB
    __shared__ __align__(16) float sWred[4][128];
    __shared__ __align__(16) int   sRow[128];
    __shared__ int   sCol[128];
    __shared__ __align__(16) float sRad[128];
    __shared__ __align__(16) float sAtt[128];
    __shared__ float sCd[128][3];

    const int tid  = threadIdx.x;
    const int w    = tid >> 6;
    const int lane = tid & 63;
    const int g    = lane >> 4;
    const int l15  = lane & 15;
    const int rh   = w >> 2;
    const int cq   = w & 3;
    const int rb   = rh * 64;
    const int e0g  = blockIdx.x * TEE;
    char* const sMb = (char*)sM;

    // ---- phase 0: indices (single int2 read), coord diff, radial ----
    if (tid < TEE) {
        const int2 rc = eidx[e0g + tid];
        sRow[tid] = rc.x; sCol[tid] = rc.y;
        const float dx = coord[rc.x * 3 + 0] - coord[rc.y * 3 + 0];
        const float dy = coord[rc.x * 3 + 1] - coord[rc.y * 3 + 1];
        const float dz = coord[rc.x * 3 + 2] - coord[rc.y * 3 + 2];
        sCd[tid][0] = dx; sCd[tid][1] = dy; sCd[tid][2] = dz;
        sRad[tid] = dx * dx + dy * dy + dz * dz;
    }
    __syncthreads();   // B0

    // ---- phase 1: m1 = silu(P[row] + Q[col] + rad*wr) -> sM (bf16 swizzled) ----
    {
        const int el  = tid >> 2;
        const int sub = tid & 3;
        const int rg = sRow[el], cg = sCol[el];
        const float rad = sRad[el];
        const unsigned short* Prow = P + (size_t)rg * DD;
        const unsigned short* Qrow = Q + (size_t)cg * DD;
        const float* We1r = We1 + 256 * DD;
#pragma unroll
        for (int i = 0; i < 4; ++i) {
            const int c8 = sub * 4 + i;
            const ushort8 pu = __builtin_bit_cast(ushort8, *(const bf16x8*)&Prow[c8 * 8]);
            const ushort8 qu = __builtin_bit_cast(ushort8, *(const bf16x8*)&Qrow[c8 * 8]);
            const float4 w0 = *(const float4*)&We1r[c8 * 8];
            const float4 w1 = *(const float4*)&We1r[c8 * 8 + 4];
            float x[8];
            x[0] = fmaf(rad, w0.x, bf2f(pu[0]) + bf2f(qu[0]));
            x[1] = fmaf(rad, w0.y, bf2f(pu[1]) + bf2f(qu[1]));
            x[2] = fmaf(rad, w0.z, bf2f(pu[2]) + bf2f(qu[2]));
            x[3] = fmaf(rad, w0.w, bf2f(pu[3]) + bf2f(qu[3]));
            x[4] = fmaf(rad, w1.x, bf2f(pu[4]) + bf2f(qu[4]));
            x[5] = fmaf(rad, w1.y, bf2f(pu[5]) + bf2f(qu[5]));
            x[6] = fmaf(rad, w1.z, bf2f(pu[6]) + bf2f(qu[6]));
            x[7] = fmaf(rad, w1.w, bf2f(pu[7]) + bf2f(qu[7]));
            uint4 pk;
            pk.x = pkbf(silu_f(x[0]), silu_f(x[1]));
            pk.y = pkbf(silu_f(x[2]), silu_f(x[3]));
            pk.z = pkbf(silu_f(x[4]), silu_f(x[5]));
            pk.w = pkbf(silu_f(x[6]), silu_f(x[7]));
            *(uint4*)(sMb + el * 256 + ((c8 * 16) ^ ((el & 7) << 4))) = pk;
        }
    }
    __syncthreads();   // B1

    f32x4 acc[4][2];

    // ---- GEMM2: m = silu(m1 @ We2 + be2) (m stays in registers) ----
    {
        float be2c[2];
#pragma unroll
        for (int ctl = 0; ctl < 2; ++ctl)
            be2c[ctl] = be2[cq * 32 + ctl * 16 + l15];
#pragma unroll
        for (int rt = 0; rt < 4; ++rt)
#pragma unroll
            for (int ctl = 0; ctl < 2; ++ctl)
#pragma unroll
                for (int j = 0; j < 4; ++j)
                    acc[rt][ctl][j] = be2c[ctl];
        const unsigned short* pWe2 = pW + 32768;
#pragma unroll 1
        for (int ks = 0; ks < 4; ++ks) {
            bf16x8 a[4];
#pragma unroll
            for (int rt = 0; rt < 4; ++rt) {
                const int row = rb + rt * 16 + l15;
                const int byc = g * 16 + ks * 64;
                a[rt] = *(const bf16x8*)(sMb + row * 256 + (byc ^ ((row & 7) << 4)));
            }
            const bf16x8 b0 = *(const bf16x8*)&pWe2[(((2 * cq + 0) * 4 + ks) * 64 + lane) * 8];
            const bf16x8 b1 = *(const bf16x8*)&pWe2[(((2 * cq + 1) * 4 + ks) * 64 + lane) * 8];
#pragma unroll
            for (int rt = 0; rt < 4; ++rt) {
                acc[rt][0] = __builtin_amdgcn_mfma_f32_16x16x32_bf16(a[rt], b0, acc[rt][0], 0, 0, 0);
                acc[rt][1] = __builtin_amdgcn_mfma_f32_16x16x32_bf16(a[rt], b1, acc[rt][1], 0, 0, 0);
            }
        }
    }
#pragma unroll
    for (int rt = 0; rt < 4; ++rt)
#pragma unroll
        for (int ctl = 0; ctl < 2; ++ctl)
#pragma unroll
            for (int j = 0; j < 4; ++j)
                acc[rt][ctl][j] = silu_f(acc[rt][ctl][j]);

    // ---- attention partials: sum_col m*Wa -> sWred[cq] ----
    {
        float wac[2];
#pragma unroll
        for (int ctl = 0; ctl < 2; ++ctl)
            wac[ctl] = Wa[cq * 32 + ctl * 16 + l15];
        float part[4][4];
#pragma unroll
        for (int rt = 0; rt < 4; ++rt)
#pragma unroll
            for (int j = 0; j < 4; ++j)
                part[rt][j] = fmaf(acc[rt][0][j], wac[0], acc[rt][1][j] * wac[1]);
#pragma unroll
        for (int msk = 1; msk < 16; msk <<= 1)
#pragma unroll
            for (int rt = 0; rt < 4; ++rt)
#pragma unroll
                for (int j = 0; j < 4; ++j)
                    part[rt][j] += __shfl_xor(part[rt][j], msk);
        if (l15 == 0) {
#pragma unroll
            for (int rt = 0; rt < 4; ++rt) {
                float4 p4 = make_float4(part[rt][0], part[rt][1], part[rt][2], part[rt][3]);
                *(float4*)&sWred[cq][rb + rt * 16 + g * 4] = p4;
            }
        }
    }
    __syncthreads();   // B2

    // ---- write m -> sM (bf16); att finalize in parallel ----
#pragma unroll
    for (int rt = 0; rt < 4; ++rt)
#pragma unroll
        for (int ctl = 0; ctl < 2; ++ctl)
#pragma unroll
            for (int j = 0; j < 4; ++j) {
                const int row = rb + rt * 16 + g * 4 + j;
                const int col = cq * 32 + ctl * 16 + l15;
                *(unsigned short*)(sMb + row * 256 + ((col * 2) ^ ((row & 7) << 4)))
                    = sbf(acc[rt][ctl][j]);
            }
    if (tid < TEE) {
        const float s = sWred[0][tid] + sWred[1][tid] + sWred[2][tid] + sWred[3][tid];
        sAtt[tid] = sigmoid_f(s + ba[0]);
    }
    __syncthreads();   // B3

    // ---- GEMMc: Y = m @ Wc1; w = sum_c silu(att*Y + bc1)*Wc2 ----
    {
        float bc1c[2];
#pragma unroll
        for (int ctl = 0; ctl < 2; ++ctl)
            bc1c[ctl] = bc1[cq * 32 + ctl * 16 + l15];
#pragma unroll
        for (int rt = 0; rt < 4; ++rt)
#pragma unroll
            for (int ctl = 0; ctl < 2; ++ctl)
#pragma unroll
                for (int j = 0; j < 4; ++j)
                    acc[rt][ctl][j] = 0.f;
        const unsigned short* pWc1 = pW + 49152;
#pragma unroll 1
        for (int ks = 0; ks < 4; ++ks) {
            bf16x8 a[4];
#pragma unroll
            for (int rt = 0; rt < 4; ++rt) {
                const int row = rb + rt * 16 + l15;
                const int byc = g * 16 + ks * 64;
                a[rt] = *(const bf16x8*)(sMb + row * 256 + (byc ^ ((row & 7) << 4)));
            }
            const bf16x8 b0 = *(const bf16x8*)&pWc1[(((2 * cq + 0) * 4 + ks) * 64 + lane) * 8];
            const bf16x8 b1 = *(const bf16x8*)&pWc1[(((2 * cq + 1) * 4 + ks) * 64 + lane) * 8];
#pragma unroll
            for (int rt = 0; rt < 4; ++rt) {
                acc[rt][0] = __builtin_amdgcn_mfma_f32_16x16x32_bf16(a[rt], b0, acc[rt][0], 0, 0, 0);
                acc[rt][1] = __builtin_amdgcn_mfma_f32_16x16x32_bf16(a[rt], b1, acc[rt][1], 0, 0, 0);
            }
        }
        float wcc[2];
#pragma unroll
        for (int ctl = 0; ctl < 2; ++ctl)
            wcc[ctl] = Wc2[cq * 32 + ctl * 16 + l15];
        float part[4][4];
#pragma unroll
        for (int rt = 0; rt < 4; ++rt) {
            const float4 a4 = *(const float4*)&sAtt[rb + rt * 16 + g * 4];
            const float at[4] = {a4.x, a4.y, a4.z, a4.w};
#pragma unroll
            for (int j = 0; j < 4; ++j) {
                const float z0 = silu_f(fmaf(at[j], acc[rt][0][j], bc1c[0]));
                const float z1 = silu_f(fmaf(at[j], acc[rt][1][j], bc1c[1]));
                part[rt][j] = fmaf(z0, wcc[0], z1 * wcc[1]);
            }
        }
#pragma unroll
        for (int msk = 1; msk < 16; msk <<= 1)
#pragma unroll
            for (int rt = 0; rt < 4; ++rt)
#pragma unroll
                for (int j = 0; j < 4; ++j)
                    part[rt][j] += __shfl_xor(part[rt][j], msk);
        if (l15 == 0) {
#pragma unroll
            for (int rt = 0; rt < 4; ++rt) {
                float4 p4 = make_float4(part[rt][0], part[rt][1], part[rt][2], part[rt][3]);
                *(float4*)&sWred[cq][rb + rt * 16 + g * 4] = p4;
            }
        }
    }
    __syncthreads();   // B4

    // ---- agg_h segmented reduce: ef[e,col] = sAtt[e]*m[e,col] on the fly ----
    {
        const int col = tid & 127;
        const int seg = tid >> 7;           // 4 segments of 32 edges
        const int ebeg = seg * 32;
        float a = 0.f;
        int cur = sRow[ebeg];
#pragma unroll 1
        for (int e = ebeg; e < ebeg + 32; ++e) {
            const int r = sRow[e];
            if (r != cur) {
                atomic_add_f(&agg_h[(size_t)cur * DD + col], a);
                a = 0.f; cur = r;
            }
            const unsigned short u =
                *(const unsigned short*)(sMb + e * 256 + ((col * 2) ^ ((e & 7) << 4)));
            a = fmaf(sAtt[e], bf2f(u), a);
        }
        atomic_add_f(&agg_h[(size_t)cur * DD + col], a);
    }

    // ---- agg_c segmented reduce (4 segs x 32 edges) ----
    if (tid < 12) {
        const int c = tid % 3;
        const int seg = tid / 3;
        const int ebeg = seg * 32;
        float a = 0.f;
        int cur = sRow[ebeg];
#pragma unroll 1
        for (int e = ebeg; e < ebeg + 32; ++e) {
            const int r = sRow[e];
            if (r != cur) {
                atomic_add_f(&agg_c[cur * 3 + c], a);
                a = 0.f; cur = r;
            }
            const float wv = sWred[0][e] + sWred[1][e] + sWred[2][e] + sWred[3][e];
            a += sCd[e][c] * wv;
        }
        atomic_add_f(&agg_c[cur * 3 + c], a);
    }
}

// ---------------------------------------------------------------------------
// node kernel: 32 nodes/block (313 blocks), 4 waves, MFMA.
// ---------------------------------------------------------------------------
__global__ __launch_bounds__(256, 2)
void node_kernel(const float* __restrict__ h, const float* __restrict__ coord,
                 const float* __restrict__ bn1, const float* __restrict__ bn2,
                 const unsigned short* __restrict__ pW,
                 const float* __restrict__ agg_h, const float* __restrict__ agg_c,
                 const int* __restrict__ cnt,
                 float* __restrict__ hout, float* __restrict__ cout)
{
    __shared__ __align__(16) unsigned short sAbuf[32 * 256];   // 16KB

    const int tid  = threadIdx.x;
    const int w    = tid >> 6;
    const int lane = tid & 63;
    const int g    = lane >> 4;
    const int l15  = lane & 15;
    const int n0   = blockIdx.x * 32;
    char* const sAb = (char*)sAbuf;

    {
        const int halfsel = (lane >= 32) ? 1 : 0;
        const int bytec   = (lane & 31) * 8 + halfsel * 256;
        const float* src  = halfsel ? agg_h : h;
#pragma unroll 4
        for (int s = 0; s < 8; ++s) {
            const int row = w * 8 + s;
            const int n = n0 + row;
            float4 v = make_float4(0.f, 0.f, 0.f, 0.f);
            if (n < NN) v = *(const float4*)&src[(size_t)n * DD + (lane & 31) * 4];
            uint2 pk;
            pk.x = pkbf(v.x, v.y);
            pk.y = pkbf(v.z, v.w);
            *(uint2*)(sAb + row * 512 + (bytec ^ ((row & 7) << 4))) = pk;
        }
    }
    __syncthreads();

    f32x4 acc[2][2];

    {
        float bc[2];
#pragma unroll
        for (int ctl = 0; ctl < 2; ++ctl)
            bc[ctl] = bn1[w * 32 + ctl * 16 + l15];
#pragma unroll
        for (int rt = 0; rt < 2; ++rt)
#pragma unroll
            for (int ctl = 0; ctl < 2; ++ctl)
#pragma unroll
                for (int j = 0; j < 4; ++j)
                    acc[rt][ctl][j] = bc[ctl];
        const unsigned short* pWn1 = pW + 65536;
#pragma unroll 1
        for (int ks = 0; ks < 8; ++ks) {
            bf16x8 a[2];
#pragma unroll
            for (int rt = 0; rt < 2; ++rt) {
                const int row = rt * 16 + l15;
                const int byc = g * 16 + ks * 64;
                a[rt] = *(const bf16x8*)(sAb + row * 512 + (byc ^ ((row & 7) << 4)));
            }
            const bf16x8 b0 = *(const bf16x8*)&pWn1[(((2 * w + 0) * 8 + ks) * 64 + lane) * 8];
            const bf16x8 b1 = *(const bf16x8*)&pWn1[(((2 * w + 1) * 8 + ks) * 64 + lane) * 8];
#pragma unroll
            for (int rt = 0; rt < 2; ++rt) {
                acc[rt][0] = __builtin_amdgcn_mfma_f32_16x16x32_bf16(a[rt], b0, acc[rt][0], 0, 0, 0);
                acc[rt][1] = __builtin_amdgcn_mfma_f32_16x16x32_bf16(a[rt], b1, acc[rt][1], 0, 0, 0);
            }
        }
    }
    __syncthreads();
#pragma unroll
    for (int rt = 0; rt < 2; ++rt)
#pragma unroll
        for (int ctl = 0; ctl < 2; ++ctl)
#pragma unroll
            for (int j = 0; j < 4; ++j) {
                const int row = rt * 16 + g * 4 + j;
                const int col = w * 32 + ctl * 16 + l15;
                *(unsigned short*)(sAb + row * 256 + ((col * 2) ^ ((row & 7) << 4)))
                    = sbf(silu_f(acc[rt][ctl][j]));
            }
    __syncthreads();

    {
        float bc[2];
#pragma unroll
        for (int ctl = 0; ctl < 2; ++ctl)
            bc[ctl] = bn2[w * 32 + ctl * 16 + l15];
#pragma unroll
        for (int rt = 0; rt < 2; ++rt)
#pragma unroll
            for (int ctl = 0; ctl < 2; ++ctl)
#pragma unroll
                for (int j = 0; j < 4; ++j)
                    acc[rt][ctl][j] = bc[ctl];
        const unsigned short* pWn2 = pW + 98304;
#pragma unroll 1
        for (int ks = 0; ks < 4; ++ks) {
            bf16x8 a[2];
#pragma unroll
            for (int rt = 0; rt < 2; ++rt) {
                const int row = rt * 16 + l15;
                const int byc = g * 16 + ks * 64;
                a[rt] = *(const bf16x8*)(sAb + row * 256 + (byc ^ ((row & 7) << 4)));
            }
            const bf16x8 b0 = *(const bf16x8*)&pWn2[(((2 * w + 0) * 4 + ks) * 64 + lane) * 8];
            const bf16x8 b1 = *(const bf16x8*)&pWn2[(((2 * w + 1) * 4 + ks) * 64 + lane) * 8];
#pragma unroll
            for (int rt = 0; rt < 2; ++rt) {
                acc[rt][0] = __builtin_amdgcn_mfma_f32_16x16x32_bf16(a[rt], b0, acc[rt][0], 0, 0, 0);
                acc[rt][1] = __builtin_amdgcn_mfma_f32_16x16x32_bf16(a[rt], b1, acc[rt][1], 0, 0, 0);
            }
        }
    }
#pragma unroll
    for (int rt = 0; rt < 2; ++rt)
#pragma unroll
        for (int ctl = 0; ctl < 2; ++ctl)
#pragma unroll
            for (int j = 0; j < 4; ++j) {
                const int row = rt * 16 + g * 4 + j;
                const int n = n0 + row;
                if (n < NN) {
                    const int col = w * 32 + ctl * 16 + l15;
                    hout[(size_t)n * DD + col] = h[(size_t)n * DD + col] + acc[rt][ctl][j];
                }
            }

    if (tid < 96) {
        const int e = tid / 3, c = tid % 3;
        const int n = n0 + e;
        if (n < NN) {
            const float cn = fmaxf((float)cnt[n], 1.0f);
            cout[n * 3 + c] = coord[n * 3 + c] + agg_c[n * 3 + c] / cn;
        }
    }
}

extern "C" void kernel_launch(void* const* d_in, const int* in_sizes, int n_in,
                              void* d_out, int out_size, void* d_ws, size_t ws_size,
                              hipStream_t stream)
{
    const float* h     = (const float*)d_in[0];
    const int*   ei    = (const int*)  d_in[1];
    const float* coord = (const float*)d_in[2];
    const float* We1   = (const float*)d_in[3];
    const float* be1   = (const float*)d_in[4];
    const float* We2   = (const float*)d_in[5];
    const float* be2   = (const float*)d_in[6];
    const float* Wa    = (const float*)d_in[7];
    const float* ba    = (const float*)d_in[8];
    const float* Wn1   = (const float*)d_in[9];
    const float* bn1   = (const float*)d_in[10];
    const float* Wn2   = (const float*)d_in[11];
    const float* bn2   = (const float*)d_in[12];
    const float* Wc1   = (const float*)d_in[13];
    const float* bc1   = (const float*)d_in[14];
    const float* Wc2   = (const float*)d_in[15];

    // ws layout
    float* agg_h   = (float*)d_ws;                   // 1,280,000 f
    float* agg_c   = agg_h + (size_t)NN * DD;        //    30,000 f
    int*   cnt_i   = (int*)(agg_c + (size_t)NN * 3); //    10,000 i
    int*   offs    = cnt_i + NN;                     //    10,016 i (incl. ctr @ +10008)
    int2*  eidx    = (int2*)(offs + 10016);          //   320,000 int2
    unsigned short* pW = (unsigned short*)(eidx + EE);     // 114,688 u16
    unsigned short* P  = pW + 114688;                      // 1,280,000 u16
    unsigned short* Q  = P + (size_t)NN * DD;              // 1,280,000 u16
    int* ctr = offs + 10008;

    // zero cnt + offs-area (incl. ctr); agg zeroed inside front_kernel
    (void)hipMemsetAsync(cnt_i, 0, (size_t)(NN + 10016) * sizeof(int), stream);

    front_kernel<<<1081, 256, 0, stream>>>(ei, cnt_i, We1, We2, Wc1, Wn1, Wn2,
                                           pW, agg_h);
    alloc_kernel<<<40, 256, 0, stream>>>(cnt_i, offs, ctr);
    mid_kernel<<<1563, 256, 0, stream>>>(ei, offs, eidx, h, be1, pW, P, Q);

    edge_kernel<<<EE / TEE, 512, 0, stream>>>(eidx, coord, P, Q, We1, be2,
                                              Wa, ba, bc1, Wc2, pW, agg_h, agg_c);

    float* hout = (float*)d_out;
    float* cout = hout + (size_t)NN * DD;
    node_kernel<<<313, 256, 0, stream>>>(h, coord, bn1, bn2, pW,
                                         agg_h, agg_c, cnt_i, hout, cout);
}

// Round 15
// 163.469 us; speedup vs baseline: 2.8055x; 1.0029x over previous
//
#include <hip/hip_runtime.h>
#include <hip/hip_bf16.h>

#define NN 10000
#define EE 320000
#define DD 128
#define TEE 128  // edges per block (edge kernel)

typedef __attribute__((ext_vector_type(8))) __bf16 bf16x8;
typedef __attribute__((ext_vector_type(2))) __bf16 bf16x2;
typedef __attribute__((ext_vector_type(8))) unsigned short ushort8;
typedef __attribute__((ext_vector_type(4))) float  f32x4;

// fast silu/sigmoid: v_rcp_f32 (~1 ulp) instead of IEEE div sequence.
__device__ __forceinline__ float silu_f(float x) {
    return x * __builtin_amdgcn_rcpf(1.0f + __expf(-x));
}
__device__ __forceinline__ float sigmoid_f(float x) {
    return __builtin_amdgcn_rcpf(1.0f + __expf(-x));
}
__device__ __forceinline__ unsigned pkbf(float a, float b) {
    bf16x2 v; v.x = (__bf16)a; v.y = (__bf16)b;
    return __builtin_bit_cast(unsigned, v);
}
__device__ __forceinline__ unsigned short sbf(float a) {
    return __builtin_bit_cast(unsigned short, (__bf16)a);
}
__device__ __forceinline__ float bf2f(unsigned short u) {
    return __builtin_bit_cast(float, (unsigned)u << 16);
}
__device__ __forceinline__ float atomic_add_f(float* p, float v) {
    return unsafeAtomicAdd(p, v);
}

// ---------------------------------------------------------------------------
// K1 fused: blocks [0,313) hist, [313,761) prep, [761,1081) zero agg (+ctr)
// ---------------------------------------------------------------------------
__global__ __launch_bounds__(256)
void front_kernel(const int* __restrict__ ei, int* __restrict__ cnt,
                  const float* __restrict__ We1, const float* __restrict__ We2,
                  const float* __restrict__ Wc1, const float* __restrict__ Wn1,
                  const float* __restrict__ Wn2, unsigned short* __restrict__ pW,
                  float* __restrict__ aggz, int* __restrict__ ctr)
{
    const int b = blockIdx.x;
    const int tid = threadIdx.x;
    if (b < 313) {
        const int t4 = b * 256 + tid;
        if (t4 < EE / 4) {
            const int4 e4 = *(const int4*)&ei[t4 * 4];
            atomicAdd(&cnt[e4.x], 1);
            atomicAdd(&cnt[e4.y], 1);
            atomicAdd(&cnt[e4.z], 1);
            atomicAdd(&cnt[e4.w], 1);
        }
    } else if (b < 761) {
        const int idx = (b - 313) * 256 + tid;
        const float* src; int loc, nks, koff = 0;
        if (idx < 16384)       { src = We1; loc = idx;         nks = 4; }
        else if (idx < 32768)  { src = We1; loc = idx - 16384; nks = 4; koff = 128; }
        else if (idx < 49152)  { src = We2; loc = idx - 32768; nks = 4; }
        else if (idx < 65536)  { src = Wc1; loc = idx - 49152; nks = 4; }
        else if (idx < 98304)  { src = Wn1; loc = idx - 65536; nks = 8; }
        else                   { src = Wn2; loc = idx - 98304; nks = 4; }
        const int per_ct = nks * 512;
        const int ct = loc / per_ct;
        const int r  = loc % per_ct;
        const int ks = r >> 9;
        const int r2 = r & 511;
        const int ln = r2 >> 3;
        const int j  = r2 & 7;
        const int k  = ks * 32 + (ln >> 4) * 8 + j + koff;
        const int n  = ct * 16 + (ln & 15);
        pW[idx] = sbf(src[k * DD + n]);
    } else {
        if (b == 761 && tid == 0) *ctr = 0;   // consumed only by alloc (next launch)
        const int base = ((b - 761) * 256 + tid) * 4;
        float4* p = (float4*)aggz;
#pragma unroll
        for (int k = 0; k < 4; ++k) {
            const int i = base + k;
            if (i < 327500) p[i] = make_float4(0.f, 0.f, 0.f, 0.f);
        }
    }
}

// ---------------------------------------------------------------------------
// alloc: order-free group allocation (grouping, not sorting, is sufficient)
// ---------------------------------------------------------------------------
__global__ __launch_bounds__(256)
void alloc_kernel(const int* __restrict__ cnt, int* __restrict__ offs,
                  int* __restrict__ ctr)
{
    const int n = blockIdx.x * 256 + threadIdx.x;
    if (n < NN) offs[n] = atomicAdd(ctr, cnt[n]);
}

// ---------------------------------------------------------------------------
// K2 fused: blocks [0,1250) scatter (post-increments offs directly),
//           [1250,1563) pq (32 nodes/block)
// ---------------------------------------------------------------------------
__global__ __launch_bounds__(256, 2)
void mid_kernel(const int* __restrict__ ei, int* __restrict__ offs,
                int2* __restrict__ eidx,
                const float* __restrict__ h, const float* __restrict__ be1,
                const unsigned short* __restrict__ pW,
                unsigned short* __restrict__ P, unsigned short* __restrict__ Q)
{
    const int b = blockIdx.x;
    const int tid = threadIdx.x;
    if (b < 1250) {
        const int e = b * 256 + tid;
        if (e < EE) {
            const int r = ei[e];
            const int c = ei[EE + e];
            const int pos = atomicAdd(&offs[r], 1);   // offs consumed in place
            eidx[pos] = make_int2(r, c);
        }
        return;
    }
    // ---- pq part: 32 nodes/block ----
    __shared__ __align__(16) unsigned short sAbuf[32 * 128];  // 8KB
    const int w    = tid >> 6;
    const int lane = tid & 63;
    const int g    = lane >> 4;
    const int l15  = lane & 15;
    const int n0   = (b - 1250) * 32;
    char* const sAb = (char*)sAbuf;

#pragma unroll
    for (int i = 0; i < 2; ++i) {
        const int idx = tid * 2 + i;          // 0..511
        const int row = idx >> 4, c = idx & 15;
        const int n = n0 + row;
        float4 a = make_float4(0.f, 0.f, 0.f, 0.f);
        float4 bb = make_float4(0.f, 0.f, 0.f, 0.f);
        if (n < NN) {
            a  = *(const float4*)&h[(size_t)n * DD + c * 8];
            bb = *(const float4*)&h[(size_t)n * DD + c * 8 + 4];
        }
        uint4 pk;
        pk.x = pkbf(a.x, a.y);  pk.y = pkbf(a.z, a.w);
        pk.z = pkbf(bb.x, bb.y); pk.w = pkbf(bb.z, bb.w);
        *(uint4*)(sAb + row * 256 + ((c * 16) ^ ((row & 7) << 4))) = pk;
    }
    __syncthreads();

    f32x4 accP[2][2], accQ[2][2];
    {
        float be1c[2];
#pragma unroll
        for (int ctl = 0; ctl < 2; ++ctl)
            be1c[ctl] = be1[w * 32 + ctl * 16 + l15];
#pragma unroll
        for (int rt = 0; rt < 2; ++rt)
#pragma unroll
            for (int ctl = 0; ctl < 2; ++ctl)
#pragma unroll
                for (int j = 0; j < 4; ++j) {
                    accP[rt][ctl][j] = be1c[ctl];
                    accQ[rt][ctl][j] = 0.f;
                }
    }
    const unsigned short* pWa = pW;
    const unsigned short* pWb = pW + 16384;
#pragma unroll 1
    for (int ks = 0; ks < 4; ++ks) {
        bf16x8 a[2];
#pragma unroll
        for (int rt = 0; rt < 2; ++rt) {
            const int row = rt * 16 + l15;
            const int byc = g * 16 + ks * 64;
            a[rt] = *(const bf16x8*)(sAb + row * 256 + (byc ^ ((row & 7) << 4)));
        }
        const bf16x8 pa0 = *(const bf16x8*)&pWa[(((2 * w + 0) * 4 + ks) * 64 + lane) * 8];
        const bf16x8 pa1 = *(const bf16x8*)&pWa[(((2 * w + 1) * 4 + ks) * 64 + lane) * 8];
        const bf16x8 pb0 = *(const bf16x8*)&pWb[(((2 * w + 0) * 4 + ks) * 64 + lane) * 8];
        const bf16x8 pb1 = *(const bf16x8*)&pWb[(((2 * w + 1) * 4 + ks) * 64 + lane) * 8];
#pragma unroll
        for (int rt = 0; rt < 2; ++rt) {
            accP[rt][0] = __builtin_amdgcn_mfma_f32_16x16x32_bf16(a[rt], pa0, accP[rt][0], 0, 0, 0);
            accP[rt][1] = __builtin_amdgcn_mfma_f32_16x16x32_bf16(a[rt], pa1, accP[rt][1], 0, 0, 0);
            accQ[rt][0] = __builtin_amdgcn_mfma_f32_16x16x32_bf16(a[rt], pb0, accQ[rt][0], 0, 0, 0);
            accQ[rt][1] = __builtin_amdgcn_mfma_f32_16x16x32_bf16(a[rt], pb1, accQ[rt][1], 0, 0, 0);
        }
    }
#pragma unroll
    for (int rt = 0; rt < 2; ++rt)
#pragma unroll
        for (int ctl = 0; ctl < 2; ++ctl)
#pragma unroll
            for (int j = 0; j < 4; ++j) {
                const int row = rt * 16 + g * 4 + j;
                const int n = n0 + row;
                if (n < NN) {
                    const int col = w * 32 + ctl * 16 + l15;
                    P[(size_t)n * DD + col] = sbf(accP[rt][ctl][j]);
                    Q[(size_t)n * DD + col] = sbf(accQ[rt][ctl][j]);
                }
            }
}

// ---------------------------------------------------------------------------
// edge kernel: 128 grouped edges/block, 8 waves (512 thr), MFMA 16x16x32.
// att factored out of GEMMc; m (not ef) lives in LDS. 5 barriers. (unchanged)
// ---------------------------------------------------------------------------
__global__ __launch_bounds__(512, 6)
void edge_kernel(const int2* __restrict__ eidx,
                 const float* __restrict__ coord,
                 const unsigned short* __restrict__ P, const unsigned short* __restrict__ Q,
                 const float* __restrict__ We1,
                 const float* __restrict__ be2,
                 const float* __restrict__ Wa, const float* __restrict__ ba,
                 const float* __restrict__ bc1, const float* __restrict__ Wc2,
                 const unsigned short* __restrict__ pW,
                 float* __restrict__ agg_h, float* __restrict__ agg_c)
{
    __shared__ __align__(16) unsigned short sM[128 * 128];   // 32KB
    __shared__ __align__(16) float sWred[4][128];
    __shared__ __align__(16) int   sRow[128];
    __shared__ int   sCol[128];
    __shared__ __align__(16) float sRad[128];
    __shared__ __align__(16) float sAtt[128];
    __shared__ float sCd[128][3];

    const int tid  = threadIdx.x;
    const int w    = tid >> 6;
    const int lane = tid & 63;
    const int g    = lane >> 4;
    const int l15  = lane & 15;
    const int rh   = w >> 2;
    const int cq   = w & 3;
    const int rb   = rh * 64;
    const int e0g  = blockIdx.x * TEE;
    char* const sMb = (char*)sM;

    // ---- phase 0: indices (single int2 read), coord diff, radial ----
    if (tid < TEE) {
        const int2 rc = eidx[e0g + tid];
        sRow[tid] = rc.x; sCol[tid] = rc.y;
        const float dx = coord[rc.x * 3 + 0] - coord[rc.y * 3 + 0];
        const float dy = coord[rc.x * 3 + 1] - coord[rc.y * 3 + 1];
        const float dz = coord[rc.x * 3 + 2] - coord[rc.y * 3 + 2];
        sCd[tid][0] = dx; sCd[tid][1] = dy; sCd[tid][2] = dz;
        sRad[tid] = dx * dx + dy * dy + dz * dz;
    }
    __syncthreads();   // B0

    // ---- phase 1: m1 = silu(P[row] + Q[col] + rad*wr) -> sM (bf16 swizzled) ----
    {
        const int el  = tid >> 2;
        const int sub = tid & 3;
        const int rg = sRow[el], cg = sCol[el];
        const float rad = sRad[el];
        const unsigned short* Prow = P + (size_t)rg * DD;
        const unsigned short* Qrow = Q + (size_t)cg * DD;
        const float* We1r = We1 + 256 * DD;
#pragma unroll
        for (int i = 0; i < 4; ++i) {
            const int c8 = sub * 4 + i;
            const ushort8 pu = __builtin_bit_cast(ushort8, *(const bf16x8*)&Prow[c8 * 8]);
            const ushort8 qu = __builtin_bit_cast(ushort8, *(const bf16x8*)&Qrow[c8 * 8]);
            const float4 w0 = *(const float4*)&We1r[c8 * 8];
            const float4 w1 = *(const float4*)&We1r[c8 * 8 + 4];
            float x[8];
            x[0] = fmaf(rad, w0.x, bf2f(pu[0]) + bf2f(qu[0]));
            x[1] = fmaf(rad, w0.y, bf2f(pu[1]) + bf2f(qu[1]));
            x[2] = fmaf(rad, w0.z, bf2f(pu[2]) + bf2f(qu[2]));
            x[3] = fmaf(rad, w0.w, bf2f(pu[3]) + bf2f(qu[3]));
            x[4] = fmaf(rad, w1.x, bf2f(pu[4]) + bf2f(qu[4]));
            x[5] = fmaf(rad, w1.y, bf2f(pu[5]) + bf2f(qu[5]));
            x[6] = fmaf(rad, w1.z, bf2f(pu[6]) + bf2f(qu[6]));
            x[7] = fmaf(rad, w1.w, bf2f(pu[7]) + bf2f(qu[7]));
            uint4 pk;
            pk.x = pkbf(silu_f(x[0]), silu_f(x[1]));
            pk.y = pkbf(silu_f(x[2]), silu_f(x[3]));
            pk.z = pkbf(silu_f(x[4]), silu_f(x[5]));
            pk.w = pkbf(silu_f(x[6]), silu_f(x[7]));
            *(uint4*)(sMb + el * 256 + ((c8 * 16) ^ ((el & 7) << 4))) = pk;
        }
    }
    __syncthreads();   // B1

    f32x4 acc[4][2];

    // ---- GEMM2: m = silu(m1 @ We2 + be2) (m stays in registers) ----
    {
        float be2c[2];
#pragma unroll
        for (int ctl = 0; ctl < 2; ++ctl)
            be2c[ctl] = be2[cq * 32 + ctl * 16 + l15];
#pragma unroll
        for (int rt = 0; rt < 4; ++rt)
#pragma unroll
            for (int ctl = 0; ctl < 2; ++ctl)
#pragma unroll
                for (int j = 0; j < 4; ++j)
                    acc[rt][ctl][j] = be2c[ctl];
        const unsigned short* pWe2 = pW + 32768;
#pragma unroll 1
        for (int ks = 0; ks < 4; ++ks) {
            bf16x8 a[4];
#pragma unroll
            for (int rt = 0; rt < 4; ++rt) {
                const int row = rb + rt * 16 + l15;
                const int byc = g * 16 + ks * 64;
                a[rt] = *(const bf16x8*)(sMb + row * 256 + (byc ^ ((row & 7) << 4)));
            }
            const bf16x8 b0 = *(const bf16x8*)&pWe2[(((2 * cq + 0) * 4 + ks) * 64 + lane) * 8];
            const bf16x8 b1 = *(const bf16x8*)&pWe2[(((2 * cq + 1) * 4 + ks) * 64 + lane) * 8];
#pragma unroll
            for (int rt = 0; rt < 4; ++rt) {
                acc[rt][0] = __builtin_amdgcn_mfma_f32_16x16x32_bf16(a[rt], b0, acc[rt][0], 0, 0, 0);
                acc[rt][1] = __builtin_amdgcn_mfma_f32_16x16x32_bf16(a[rt], b1, acc[rt][1], 0, 0, 0);
            }
        }
    }
#pragma unroll
    for (int rt = 0; rt < 4; ++rt)
#pragma unroll
        for (int ctl = 0; ctl < 2; ++ctl)
#pragma unroll
            for (int j = 0; j < 4; ++j)
                acc[rt][ctl][j] = silu_f(acc[rt][ctl][j]);

    // ---- attention partials: sum_col m*Wa -> sWred[cq] ----
    {
        float wac[2];
#pragma unroll
        for (int ctl = 0; ctl < 2; ++ctl)
            wac[ctl] = Wa[cq * 32 + ctl * 16 + l15];
        float part[4][4];
#pragma unroll
        for (int rt = 0; rt < 4; ++rt)
#pragma unroll
            for (int j = 0; j < 4; ++j)
                part[rt][j] = fmaf(acc[rt][0][j], wac[0], acc[rt][1][j] * wac[1]);
#pragma unroll
        for (int msk = 1; msk < 16; msk <<= 1)
#pragma unroll
            for (int rt = 0; rt < 4; ++rt)
#pragma unroll
                for (int j = 0; j < 4; ++j)
                    part[rt][j] += __shfl_xor(part[rt][j], msk);
        if (l15 == 0) {
#pragma unroll
            for (int rt = 0; rt < 4; ++rt) {
                float4 p4 = make_float4(part[rt][0], part[rt][1], part[rt][2], part[rt][3]);
                *(float4*)&sWred[cq][rb + rt * 16 + g * 4] = p4;
            }
        }
    }
    __syncthreads();   // B2

    // ---- write m -> sM (bf16); att finalize in parallel ----
#pragma unroll
    for (int rt = 0; rt < 4; ++rt)
#pragma unroll
        for (int ctl = 0; ctl < 2; ++ctl)
#pragma unroll
            for (int j = 0; j < 4; ++j) {
                const int row = rb + rt * 16 + g * 4 + j;
                const int col = cq * 32 + ctl * 16 + l15;
                *(unsigned short*)(sMb + row * 256 + ((col * 2) ^ ((row & 7) << 4)))
                    = sbf(acc[rt][ctl][j]);
            }
    if (tid < TEE) {
        const float s = sWred[0][tid] + sWred[1][tid] + sWred[2][tid] + sWred[3][tid];
        sAtt[tid] = sigmoid_f(s + ba[0]);
    }
    __syncthreads();   // B3

    // ---- GEMMc: Y = m @ Wc1; w = sum_c silu(att*Y + bc1)*Wc2 ----
    {
        float bc1c[2];
#pragma unroll
        for (int ctl = 0; ctl < 2; ++ctl)
            bc1c[ctl] = bc1[cq * 32 + ctl * 16 + l15];
#pragma unroll
        for (int rt = 0; rt < 4; ++rt)
#pragma unroll
            for (int ctl = 0; ctl < 2; ++ctl)
#pragma unroll
                for (int j = 0; j < 4; ++j)
                    acc[rt][ctl][j] = 0.f;
        const unsigned short* pWc1 = pW + 49152;
#pragma unroll 1
        for (int ks = 0; ks < 4; ++ks) {
            bf16x8 a[4];
#pragma unroll
            for (int rt = 0; rt < 4; ++rt) {
                const int row = rb + rt * 16 + l15;
                const int byc = g * 16 + ks * 64;
                a[rt] = *(const bf16x8*)(sMb + row * 256 + (byc ^ ((row & 7) << 4)));
            }
            const bf16x8 b0 = *(const bf16x8*)&pWc1[(((2 * cq + 0) * 4 + ks) * 64 + lane) * 8];
            const bf16x8 b1 = *(const bf16x8*)&pWc1[(((2 * cq + 1) * 4 + ks) * 64 + lane) * 8];
#pragma unroll
            for (int rt = 0; rt < 4; ++rt) {
                acc[rt][0] = __builtin_amdgcn_mfma_f32_16x16x32_bf16(a[rt], b0, acc[rt][0], 0, 0, 0);
                acc[rt][1] = __builtin_amdgcn_mfma_f32_16x16x32_bf16(a[rt], b1, acc[rt][1], 0, 0, 0);
            }
        }
        float wcc[2];
#pragma unroll
        for (int ctl = 0; ctl < 2; ++ctl)
            wcc[ctl] = Wc2[cq * 32 + ctl * 16 + l15];
        float part[4][4];
#pragma unroll
        for (int rt = 0; rt < 4; ++rt) {
            const float4 a4 = *(const float4*)&sAtt[rb + rt * 16 + g * 4];
            const float at[4] = {a4.x, a4.y, a4.z, a4.w};
#pragma unroll
            for (int j = 0; j < 4; ++j) {
                const float z0 = silu_f(fmaf(at[j], acc[rt][0][j], bc1c[0]));
                const float z1 = silu_f(fmaf(at[j], acc[rt][1][j], bc1c[1]));
                part[rt][j] = fmaf(z0, wcc[0], z1 * wcc[1]);
            }
        }
#pragma unroll
        for (int msk = 1; msk < 16; msk <<= 1)
#pragma unroll
            for (int rt = 0; rt < 4; ++rt)
#pragma unroll
                for (int j = 0; j < 4; ++j)
                    part[rt][j] += __shfl_xor(part[rt][j], msk);
        if (l15 == 0) {
#pragma unroll
            for (int rt = 0; rt < 4; ++rt) {
                float4 p4 = make_float4(part[rt][0], part[rt][1], part[rt][2], part[rt][3]);
                *(float4*)&sWred[cq][rb + rt * 16 + g * 4] = p4;
            }
        }
    }
    __syncthreads();   // B4

    // ---- agg_h segmented reduce: ef[e,col] = sAtt[e]*m[e,col] on the fly ----
    {
        const int col = tid & 127;
        const int seg = tid >> 7;           // 4 segments of 32 edges
        const int ebeg = seg * 32;
        float a = 0.f;
        int cur = sRow[ebeg];
#pragma unroll 1
        for (int e = ebeg; e < ebeg + 32; ++e) {
            const int r = sRow[e];
            if (r != cur) {
                atomic_add_f(&agg_h[(size_t)cur * DD + col], a);
                a = 0.f; cur = r;
            }
            const unsigned short u =
                *(const unsigned short*)(sMb + e * 256 + ((col * 2) ^ ((e & 7) << 4)));
            a = fmaf(sAtt[e], bf2f(u), a);
        }
        atomic_add_f(&agg_h[(size_t)cur * DD + col], a);
    }

    // ---- agg_c segmented reduce (4 segs x 32 edges) ----
    if (tid < 12) {
        const int c = tid % 3;
        const int seg = tid / 3;
        const int ebeg = seg * 32;
        float a = 0.f;
        int cur = sRow[ebeg];
#pragma unroll 1
        for (int e = ebeg; e < ebeg + 32; ++e) {
            const int r = sRow[e];
            if (r != cur) {
                atomic_add_f(&agg_c[cur * 3 + c], a);
                a = 0.f; cur = r;
            }
            const float wv = sWred[0][e] + sWred[1][e] + sWred[2][e] + sWred[3][e];
            a += sCd[e][c] * wv;
        }
        atomic_add_f(&agg_c[cur * 3 + c], a);
    }
}

// ---------------------------------------------------------------------------
// node kernel: 32 nodes/block (313 blocks), 4 waves, MFMA.
// Vectorized epilogue: acc -> LDS fp32 -> float4 h-load + float4 store.
// ---------------------------------------------------------------------------
__global__ __launch_bounds__(256, 2)
void node_kernel(const float* __restrict__ h, const float* __restrict__ coord,
                 const float* __restrict__ bn1, const float* __restrict__ bn2,
                 const unsigned short* __restrict__ pW,
                 const float* __restrict__ agg_h, const float* __restrict__ agg_c,
                 const int* __restrict__ cnt,
                 float* __restrict__ hout, float* __restrict__ cout)
{
    __shared__ __align__(16) unsigned short sAbuf[32 * 256];   // 16KB

    const int tid  = threadIdx.x;
    const int w    = tid >> 6;
    const int lane = tid & 63;
    const int g    = lane >> 4;
    const int l15  = lane & 15;
    const int n0   = blockIdx.x * 32;
    char* const sAb = (char*)sAbuf;
    float* const sF = (float*)sAbuf;   // fp32 [32][128] view for epilogue

    {
        const int halfsel = (lane >= 32) ? 1 : 0;
        const int bytec   = (lane & 31) * 8 + halfsel * 256;
        const float* src  = halfsel ? agg_h : h;
#pragma unroll 4
        for (int s = 0; s < 8; ++s) {
            const int row = w * 8 + s;
            const int n = n0 + row;
            float4 v = make_float4(0.f, 0.f, 0.f, 0.f);
            if (n < NN) v = *(const float4*)&src[(size_t)n * DD + (lane & 31) * 4];
            uint2 pk;
            pk.x = pkbf(v.x, v.y);
            pk.y = pkbf(v.z, v.w);
            *(uint2*)(sAb + row * 512 + (bytec ^ ((row & 7) << 4))) = pk;
        }
    }
    __syncthreads();

    f32x4 acc[2][2];

    {
        float bc[2];
#pragma unroll
        for (int ctl = 0; ctl < 2; ++ctl)
            bc[ctl] = bn1[w * 32 + ctl * 16 + l15];
#pragma unroll
        for (int rt = 0; rt < 2; ++rt)
#pragma unroll
            for (int ctl = 0; ctl < 2; ++ctl)
#pragma unroll
                for (int j = 0; j < 4; ++j)
                    acc[rt][ctl][j] = bc[ctl];
        const unsigned short* pWn1 = pW + 65536;
#pragma unroll 1
        for (int ks = 0; ks < 8; ++ks) {
            bf16x8 a[2];
#pragma unroll
            for (int rt = 0; rt < 2; ++rt) {
                const int row = rt * 16 + l15;
                const int byc = g * 16 + ks * 64;
                a[rt] = *(const bf16x8*)(sAb + row * 512 + (byc ^ ((row & 7) << 4)));
            }
            const bf16x8 b0 = *(const bf16x8*)&pWn1[(((2 * w + 0) * 8 + ks) * 64 + lane) * 8];
            const bf16x8 b1 = *(const bf16x8*)&pWn1[(((2 * w + 1) * 8 + ks) * 64 + lane) * 8];
#pragma unroll
            for (int rt = 0; rt < 2; ++rt) {
                acc[rt][0] = __builtin_amdgcn_mfma_f32_16x16x32_bf16(a[rt], b0, acc[rt][0], 0, 0, 0);
                acc[rt][1] = __builtin_amdgcn_mfma_f32_16x16x32_bf16(a[rt], b1, acc[rt][1], 0, 0, 0);
            }
        }
    }
    __syncthreads();
#pragma unroll
    for (int rt = 0; rt < 2; ++rt)
#pragma unroll
        for (int ctl = 0; ctl < 2; ++ctl)
#pragma unroll
            for (int j = 0; j < 4; ++j) {
                const int row = rt * 16 + g * 4 + j;
                const int col = w * 32 + ctl * 16 + l15;
                *(unsigned short*)(sAb + row * 256 + ((col * 2) ^ ((row & 7) << 4)))
                    = sbf(silu_f(acc[rt][ctl][j]));
            }
    __syncthreads();

    {
        float bc[2];
#pragma unroll
        for (int ctl = 0; ctl < 2; ++ctl)
            bc[ctl] = bn2[w * 32 + ctl * 16 + l15];
#pragma unroll
        for (int rt = 0; rt < 2; ++rt)
#pragma unroll
            for (int ctl = 0; ctl < 2; ++ctl)
#pragma unroll
                for (int j = 0; j < 4; ++j)
                    acc[rt][ctl][j] = bc[ctl];
        const unsigned short* pWn2 = pW + 98304;
#pragma unroll 1
        for (int ks = 0; ks < 4; ++ks) {
            bf16x8 a[2];
#pragma unroll
            for (int rt = 0; rt < 2; ++rt) {
                const int row = rt * 16 + l15;
                const int byc = g * 16 + ks * 64;
                a[rt] = *(const bf16x8*)(sAb + row * 256 + (byc ^ ((row & 7) << 4)));
            }
            const bf16x8 b0 = *(const bf16x8*)&pWn2[(((2 * w + 0) * 4 + ks) * 64 + lane) * 8];
            const bf16x8 b1 = *(const bf16x8*)&pWn2[(((2 * w + 1) * 4 + ks) * 64 + lane) * 8];
#pragma unroll
            for (int rt = 0; rt < 2; ++rt) {
                acc[rt][0] = __builtin_amdgcn_mfma_f32_16x16x32_bf16(a[rt], b0, acc[rt][0], 0, 0, 0);
                acc[rt][1] = __builtin_amdgcn_mfma_f32_16x16x32_bf16(a[rt], b1, acc[rt][1], 0, 0, 0);
            }
        }
    }
    // ---- coord out (independent of epilogue LDS reuse) ----
    if (tid < 96) {
        const int e = tid / 3, c = tid % 3;
        const int n = n0 + e;
        if (n < NN) {
            const float cn = fmaxf((float)cnt[n], 1.0f);
            cout[n * 3 + c] = coord[n * 3 + c] + agg_c[n * 3 + c] / cn;
        }
    }
    __syncthreads();   // all GEMM2 reads of sAb done

    // ---- acc -> LDS fp32 [32][128] ----
#pragma unroll
    for (int rt = 0; rt < 2; ++rt)
#pragma unroll
        for (int ctl = 0; ctl < 2; ++ctl)
#pragma unroll
            for (int j = 0; j < 4; ++j) {
                const int row = rt * 16 + g * 4 + j;
                const int col = w * 32 + ctl * 16 + l15;
                sF[row * 128 + col] = acc[rt][ctl][j];
            }
    __syncthreads();

    // ---- vectorized residual write: hout = h + out (float4) ----
#pragma unroll
    for (int i = 0; i < 4; ++i) {
        const int idx = tid * 4 + i;            // 0..1023 float4s
        const int row = idx >> 5, c4 = (idx & 31) * 4;
        const int n = n0 + row;
        if (n < NN) {
            const float4 o = *(const float4*)&sF[row * 128 + c4];
            const float4 hv = *(const float4*)&h[(size_t)n * DD + c4];
            float4 r;
            r.x = hv.x + o.x; r.y = hv.y + o.y;
            r.z = hv.z + o.z; r.w = hv.w + o.w;
            *(float4*)&hout[(size_t)n * DD + c4] = r;
        }
    }
}

extern "C" void kernel_launch(void* const* d_in, const int* in_sizes, int n_in,
                              void* d_out, int out_size, void* d_ws, size_t ws_size,
                              hipStream_t stream)
{
    const float* h     = (const float*)d_in[0];
    const int*   ei    = (const int*)  d_in[1];
    const float* coord = (const float*)d_in[2];
    const float* We1   = (const float*)d_in[3];
    const float* be1   = (const float*)d_in[4];
    const float* We2   = (const float*)d_in[5];
    const float* be2   = (const float*)d_in[6];
    const float* Wa    = (const float*)d_in[7];
    const float* ba    = (const float*)d_in[8];
    const float* Wn1   = (const float*)d_in[9];
    const float* bn1   = (const float*)d_in[10];
    const float* Wn2   = (const float*)d_in[11];
    const float* bn2   = (const float*)d_in[12];
    const float* Wc1   = (const float*)d_in[13];
    const float* bc1   = (const float*)d_in[14];
    const float* Wc2   = (const float*)d_in[15];

    // ws layout
    float* agg_h   = (float*)d_ws;                   // 1,280,000 f
    float* agg_c   = agg_h + (size_t)NN * DD;        //    30,000 f
    int*   cnt_i   = (int*)(agg_c + (size_t)NN * 3); //    10,000 i
    int*   offs    = cnt_i + NN;                     //    10,016 i (incl. ctr @ +10008)
    int2*  eidx    = (int2*)(offs + 10016);          //   320,000 int2
    unsigned short* pW = (unsigned short*)(eidx + EE);     // 114,688 u16
    unsigned short* P  = pW + 114688;                      // 1,280,000 u16
    unsigned short* Q  = P + (size_t)NN * DD;              // 1,280,000 u16
    int* ctr = offs + 10008;

    // zero only cnt (40KB); ctr zeroed in front_kernel; agg zeroed in front_kernel
    (void)hipMemsetAsync(cnt_i, 0, (size_t)NN * sizeof(int), stream);

    front_kernel<<<1081, 256, 0, stream>>>(ei, cnt_i, We1, We2, Wc1, Wn1, Wn2,
                                           pW, agg_h, ctr);
    alloc_kernel<<<40, 256, 0, stream>>>(cnt_i, offs, ctr);
    mid_kernel<<<1563, 256, 0, stream>>>(ei, offs, eidx, h, be1, pW, P, Q);

    edge_kernel<<<EE / TEE, 512, 0, stream>>>(eidx, coord, P, Q, We1, be2,
                                              Wa, ba, bc1, Wc2, pW, agg_h, agg_c);

    float* hout = (float*)d_out;
    float* cout = hout + (size_t)NN * DD;
    node_kernel<<<313, 256, 0, stream>>>(h, coord, bn1, bn2, pW,
                                         agg_h, agg_c, cnt_i, hout, cout);
}